// Round 13
// baseline (70.009 us; speedup 1.0000x reference)
//
#include <hip/hip_runtime.h>
#include <hip/hip_bf16.h>
#include <math.h>

#define NR 8
#define NB 8
#define NH 32
#define NKVH 8
#define NG 4
#define ND 128
#define NDV 128
#define NDH 64                // dv half handled per block
#define NPAGE 2048
#define KSTR (NKVH*ND)        // 1024 floats per page (all kvh slices)
#define NCH 8                 // page-chunks per rank
#define CHUNK 256             // pages per chunk
#define NPART (NR*NCH)        // 64 partial slots
#define PSTRIDE (NB*NKVH*NG)  // 256 output rows
#define QSCALE 0.088388347648318447f
#define DEFER_THR 8.0f

typedef __attribute__((ext_vector_type(8))) short bf16x8;
typedef __attribute__((ext_vector_type(4))) float f32x4;

static __device__ __forceinline__ short f2bf(float x) {
  __hip_bfloat16 h = __float2bfloat16(x);
  return __builtin_bit_cast(short, h);
}

// async global->LDS, 16B per lane; LDS dest = wave-uniform base + lane*16
static __device__ __forceinline__ void gload_lds16(const float* g, float* l) {
  __builtin_amdgcn_global_load_lds(
      (__attribute__((address_space(1))) void*)g,
      (__attribute__((address_space(3))) void*)l, 16, 0, 0);
}

// ---------------- histogram: cntf[r][b][pg] = (float) multiplicity
__global__ __launch_bounds__(256) void build_counts(
    const int* __restrict__ kv_lens, const int* __restrict__ bt_all,
    float* __restrict__ cntf) {
  const int rb = blockIdx.x;             // r*NB + b
  __shared__ int h[NPAGE];
  for (int i = threadIdx.x; i < NPAGE; i += 256) h[i] = 0;
  __syncthreads();
  const int len = kv_lens[rb];
  const int* bt = bt_all + (size_t)rb * NPAGE;
  for (int i = threadIdx.x; i < len; i += 256) atomicAdd(&h[bt[i]], 1);
  __syncthreads();
  float* o = cntf + (size_t)rb * NPAGE;
  for (int i = threadIdx.x; i < NPAGE; i += 256) o[i] = (float)h[i];
}

// ---------------- MFMA weighted-stream attention partials, 2-deep pipelined,
// dv-SPLIT: block = (r, kvh, chunk, gp, dh); 4 waves = 4 page-quarters.
// Each wave: 64 pages x 2 heads x 64 dv dims (dh half). QK+softmax are
// recomputed by the dh-sibling (MFMA ~free; K dedups in L2); V staging and
// O-acc halve -> LDS 38.5KB -> 4 blocks/CU = 16 waves/CU (2x round 12).
// NOTE launch_bounds arg2: on this toolchain arg2=4 caps VGPR at 64 (spills).
__global__ __launch_bounds__(256, 1) void attn_partial(
    const float* __restrict__ q,
    const float* __restrict__ k_cache,
    const float* __restrict__ v_cache,
    const float* __restrict__ cntf,
    float* __restrict__ ws_out,   // [NPART][NB][NKVH][NG][NDV]
    float* __restrict__ ws_lse)   // [NPART][NB][NKVH][NG]
{
  const int bid   = blockIdx.x;
  const int r     = bid & 7;              // XCD swizzle: rank pinned per XCD
  const int kvh   = (bid >> 3) & 7;
  const int dh    = (bid >> 6) & 1;       // dv half (sibling co-resident)
  const int gp    = (bid >> 7) & 1;       // heads {2gp, 2gp+1}
  const int chunk = bid >> 8;             // 0..7

  const int tid  = threadIdx.x;
  const int wid  = tid >> 6;
  const int lane = tid & 63;
  const int col  = lane & 15;     // score: page-in-tile | PV: dim-block
  const int hq   = lane >> 4;     // score: k-quarter    | PV: qrow-quad

  // V half-dbuf (wave-private), union'd with the post-loop merge buffer.
  __shared__ float UN[4][2][1024];        // 32 KB
  __shared__ float Plds[4][16][20];       // [pg][qr], stride 20 (16B-aligned)
  __shared__ float Sml[4][16][2];

  // ---- Q A-frags (bf16, pre-scaled)
  bf16x8 qf[4];
  {
    const int qrow = col;
    const int b = qrow & 7;
    const int g = gp * 2 + (qrow >> 3);
    const float* qp = q + ((size_t)b * NH + kvh * NG + g) * ND + hq * 8;
#pragma unroll
    for (int st = 0; st < 4; ++st) {
      const float4 t0 = *(const float4*)(qp + st * 32);
      const float4 t1 = *(const float4*)(qp + st * 32 + 4);
      bf16x8 f;
      f[0] = f2bf(t0.x * QSCALE); f[1] = f2bf(t0.y * QSCALE);
      f[2] = f2bf(t0.z * QSCALE); f[3] = f2bf(t0.w * QSCALE);
      f[4] = f2bf(t1.x * QSCALE); f[5] = f2bf(t1.y * QSCALE);
      f[6] = f2bf(t1.z * QSCALE); f[7] = f2bf(t1.w * QSCALE);
      qf[st] = f;
    }
  }

  const int pg0w = chunk * CHUNK + wid * 64;   // wave's first page
  const float* Kb = k_cache + (size_t)r * NPAGE * KSTR + kvh * ND;
  const float* Vb = v_cache + (size_t)r * NPAGE * KSTR + kvh * NDV + dh * NDH;

  // prefetch macros: 4 stage + 8 K + 4 cw = 16 VMEM ops per tile
#define STAGE_V(bf, pgt)                                                     \
  {                                                                          \
    _Pragma("unroll")                                                        \
    for (int i = 0; i < 4; ++i) {                                            \
      const float* s_ =                                                      \
          Vb + (size_t)((pgt) + 4 * i + (lane >> 4)) * KSTR + (lane & 15) * 4; \
      gload_lds16(s_, &UN[wid][bf][i * 256]);                                \
    }                                                                        \
  }
#define KLOAD(dst, pgt)                                                      \
  {                                                                          \
    const float* kp_ = Kb + (size_t)((pgt) + col) * KSTR + hq * 8;           \
    _Pragma("unroll")                                                        \
    for (int st = 0; st < 4; ++st) {                                         \
      dst[2 * st]     = *(const float4*)(kp_ + st * 32);                     \
      dst[2 * st + 1] = *(const float4*)(kp_ + st * 32 + 4);                 \
    }                                                                        \
  }
#define CWLOAD(dst, pgt)                                                     \
  {                                                                          \
    _Pragma("unroll")                                                        \
    for (int rg = 0; rg < 4; ++rg)                                           \
      dst[rg] = cntf[((size_t)(r * NB + ((hq * 4 + rg) & 7))) * NPAGE +      \
                     (pgt) + col];                                           \
  }

  float4 kr[2][8];
  float  cwl[2][4];

  // prologue: prefetch tile 0
  STAGE_V(0, pg0w);
  KLOAD(kr[0], pg0w);
  CWLOAD(cwl[0], pg0w);

  float m[4], l[4];
#pragma unroll
  for (int g4 = 0; g4 < 4; ++g4) { m[g4] = -INFINITY; l[g4] = 0.f; }
  f32x4 O[4];                    // row hq*4+rg, dims dh*64 + col*4..+3
#pragma unroll
  for (int rg = 0; rg < 4; ++rg) O[rg] = (f32x4){0.f, 0.f, 0.f, 0.f};

#pragma unroll
  for (int t = 0; t < 4; ++t) {
    const int pgt = pg0w + t * 16;
    const int bf  = t & 1;

    if (t < 3) {                         // prefetch t+1, then counted wait
      STAGE_V(bf ^ 1, pgt + 16);
      KLOAD(kr[(t + 1) & 1], pgt + 16);
      CWLOAD(cwl[(t + 1) & 1], pgt + 16);
      asm volatile("s_waitcnt vmcnt(16)" ::: "memory");
    } else {
      asm volatile("s_waitcnt vmcnt(0)" ::: "memory");
    }

    // ---- QK^T: 4 MFMAs (K from prefetched regs, cvt to bf16 now)
    f32x4 acc = (f32x4){0.f, 0.f, 0.f, 0.f};
#pragma unroll
    for (int st = 0; st < 4; ++st) {
      const float4 a0 = kr[bf][2 * st];
      const float4 a1 = kr[bf][2 * st + 1];
      bf16x8 kf;
      kf[0] = f2bf(a0.x); kf[1] = f2bf(a0.y); kf[2] = f2bf(a0.z); kf[3] = f2bf(a0.w);
      kf[4] = f2bf(a1.x); kf[5] = f2bf(a1.y); kf[6] = f2bf(a1.z); kf[7] = f2bf(a1.w);
      acc = __builtin_amdgcn_mfma_f32_16x16x32_bf16(qf[st], kf, acc, 0, 0, 0);
    }

    // ---- batched softmax (counts as weights), defer-max.
    float s[4], tm[4];
#pragma unroll
    for (int rg = 0; rg < 4; ++rg) { s[rg] = acc[rg]; tm[rg] = acc[rg]; }
#pragma unroll
    for (int mk = 1; mk <= 8; mk <<= 1)
#pragma unroll
      for (int rg = 0; rg < 4; ++rg) tm[rg] = fmaxf(tm[rg], __shfl_xor(tm[rg], mk));

    bool need = false;
#pragma unroll
    for (int rg = 0; rg < 4; ++rg) need |= (tm[rg] > m[rg] + DEFER_THR);
    const bool doresc = __any(need);
    float sc[4];
    if (doresc) {
#pragma unroll
      for (int rg = 0; rg < 4; ++rg) {
        const float mn = fmaxf(m[rg], tm[rg]);
        sc[rg] = __expf(m[rg] - mn);     // first tile: exp(-inf)=0
        m[rg] = mn; l[rg] *= sc[rg];
      }
    }

    float p[4], ts[4];
#pragma unroll
    for (int rg = 0; rg < 4; ++rg) {
      p[rg] = cwl[bf][rg] * __expf(s[rg] - m[rg]);
      ts[rg] = p[rg];
    }
#pragma unroll
    for (int mk = 1; mk <= 8; mk <<= 1)
#pragma unroll
      for (int rg = 0; rg < 4; ++rg) ts[rg] += __shfl_xor(ts[rg], mk);
#pragma unroll
    for (int rg = 0; rg < 4; ++rg) l[rg] += ts[rg];

    // P -> LDS: one b128 write (rows hq*4..+3 contiguous, row pg=col)
    {
      f32x4 pv = (f32x4){p[0], p[1], p[2], p[3]};
      *(f32x4*)&Plds[wid][col][hq * 4] = pv;
    }

    if (doresc) {                        // O rows == softmax rows: sc in-register
#pragma unroll
      for (int rg = 0; rg < 4; ++rg) O[rg] *= sc[rg];
    }

    // ---- PV from LDS-staged half-V: 2 DS reads per page (1 V + 1 P)
#pragma unroll 4
    for (int pg = 0; pg < 16; ++pg) {
      const f32x4 pw = *(const f32x4*)&Plds[wid][pg][hq * 4];
      const f32x4 va = *(const f32x4*)&UN[wid][bf][pg * 64 + col * 4];
#pragma unroll
      for (int rg = 0; rg < 4; ++rg) O[rg] += pw[rg] * va;
    }
  }

  // ---- merge: overlay Sacc onto the (now dead) V buffers
  __syncthreads();                       // all waves done reading UN
  float* Sacc = &UN[0][0][0];            // rows of 68 floats: [w*16+qr]
  if (col == 0) {
#pragma unroll
    for (int rg = 0; rg < 4; ++rg) {
      Sml[wid][hq * 4 + rg][0] = m[rg];
      Sml[wid][hq * 4 + rg][1] = l[rg];
    }
  }
#pragma unroll
  for (int rg = 0; rg < 4; ++rg) {
    const int qr = hq * 4 + rg;
    *(f32x4*)&Sacc[(wid * 16 + qr) * 68 + col * 4] = O[rg];
  }
  __syncthreads();

  // ---- 4-way wave merge, normalize, write half-row partial
  const int qr = tid >> 4;        // 0..15
  const int db = tid & 15;        // 4 dims each
  float M = -INFINITY;
#pragma unroll
  for (int w = 0; w < 4; ++w) M = fmaxf(M, Sml[w][qr][0]);
  float wgt[4];
  float L = 0.f;
#pragma unroll
  for (int w = 0; w < 4; ++w) {
    const float mw = Sml[w][qr][0];
    wgt[w] = (mw > -1e37f) ? __expf(mw - M) : 0.f;
    L += Sml[w][qr][1] * wgt[w];
  }
  const float inv = (L > 0.f) ? 1.f / L : 0.f;

  const int pi = r * NCH + chunk;
  const int b  = qr & 7;
  const int g  = gp * 2 + (qr >> 3);
  const size_t prow = (((size_t)pi * NB + b) * NKVH + kvh) * NG + g;
  {
    float4 o = make_float4(0.f, 0.f, 0.f, 0.f);
#pragma unroll
    for (int w = 0; w < 4; ++w) {
      const float* s4 = &Sacc[(w * 16 + qr) * 68 + db * 4];
      o.x += s4[0] * wgt[w]; o.y += s4[1] * wgt[w];
      o.z += s4[2] * wgt[w]; o.w += s4[3] * wgt[w];
    }
    o.x *= inv; o.y *= inv; o.z *= inv; o.w *= inv;
    *(float4*)(ws_out + prow * NDV + dh * NDH + db * 4) = o;
  }
  // both dh siblings compute identical (M,L): duplicate write is benign/deterministic
  if (db == 0) ws_lse[prow] = (L > 0.f) ? (M + __logf(L)) : -1e30f;
}

// ---------------- combine over NPART partials per (b,kvh,g)
__global__ __launch_bounds__(128) void attn_combine(
    const float* __restrict__ ws_out,
    const float* __restrict__ ws_lse,
    float* __restrict__ out)
{
  const int bkg = blockIdx.x;
  const int d   = threadIdx.x;

  float mg = -INFINITY;
#pragma unroll 16
  for (int p = 0; p < NPART; ++p)
    mg = fmaxf(mg, ws_lse[p * PSTRIDE + bkg]);

  float denom = 0.f, acc = 0.f;
#pragma unroll 8
  for (int p = 0; p < NPART; ++p) {
    const float e = __expf(ws_lse[p * PSTRIDE + bkg] - mg);
    denom += e;
    acc += e * ws_out[((size_t)p * PSTRIDE + bkg) * NDV + d];
  }
  out[(size_t)bkg * NDV + d] = acc / denom;
}

extern "C" void kernel_launch(void* const* d_in, const int* in_sizes, int n_in,
                              void* d_out, int out_size, void* d_ws, size_t ws_size,
                              hipStream_t stream) {
  const float* q        = (const float*)d_in[0];
  const float* k_cache  = (const float*)d_in[1];
  const float* v_cache  = (const float*)d_in[2];
  const int*   kv_lens  = (const int*)d_in[3];
  const int*   bt       = (const int*)d_in[4];
  float* out = (float*)d_out;

  float* ws_out = (float*)d_ws;                                   // 8.39 MB
  float* ws_lse = ws_out + (size_t)NPART * PSTRIDE * NDV;         // 64 KB
  float* cntf   = ws_lse + NPART * PSTRIDE;                       // 512 KB

  build_counts<<<NR * NB, 256, 0, stream>>>(kv_lens, bt, cntf);
  attn_partial<<<NR * NKVH * NCH * 2 * 2, 256, 0, stream>>>(
      q, k_cache, v_cache, cntf, ws_out, ws_lse);
  attn_combine<<<NB * NKVH * NG, NDV, 0, stream>>>(ws_out, ws_lse, out);
}

// Round 14
// 67.810 us; speedup vs baseline: 1.0324x; 1.0324x over previous
//
#include <hip/hip_runtime.h>
#include <hip/hip_bf16.h>
#include <math.h>

#define NR 8
#define NB 8
#define NH 32
#define NKVH 8
#define NG 4
#define ND 128
#define NDV 128
#define NDH 64                // dv half handled per block
#define NPAGE 2048
#define KSTR (NKVH*ND)        // 1024 floats per page (all kvh slices)
#define NCH 8                 // page-chunks per rank
#define CHUNK 256             // pages per chunk
#define NPART (NR*NCH)        // 64 partial slots
#define PSTRIDE (NB*NKVH*NG)  // 256 output rows
#define QSCALE 0.088388347648318447f

typedef __attribute__((ext_vector_type(8))) short bf16x8;
typedef __attribute__((ext_vector_type(4))) float f32x4;

static __device__ __forceinline__ short f2bf(float x) {
  __hip_bfloat16 h = __float2bfloat16(x);
  return __builtin_bit_cast(short, h);
}

// async global->LDS, 16B per lane; LDS dest = wave-uniform base + lane*16
static __device__ __forceinline__ void gload_lds16(const float* g, float* l) {
  __builtin_amdgcn_global_load_lds(
      (__attribute__((address_space(1))) void*)g,
      (__attribute__((address_space(3))) void*)l, 16, 0, 0);
}

// ---------------- histogram: cntf[r][b][pg] = (float) multiplicity
__global__ __launch_bounds__(256) void build_counts(
    const int* __restrict__ kv_lens, const int* __restrict__ bt_all,
    float* __restrict__ cntf) {
  const int rb = blockIdx.x;             // r*NB + b
  __shared__ int h[NPAGE];
  for (int i = threadIdx.x; i < NPAGE; i += 256) h[i] = 0;
  __syncthreads();
  const int len = kv_lens[rb];
  const int* bt = bt_all + (size_t)rb * NPAGE;
  for (int i = threadIdx.x; i < len; i += 256) atomicAdd(&h[bt[i]], 1);
  __syncthreads();
  float* o = cntf + (size_t)rb * NPAGE;
  for (int i = threadIdx.x; i < NPAGE; i += 256) o[i] = (float)h[i];
}

// ---------------- MFMA weighted-stream attention partials, 2-deep pipelined,
// dv-split, SHUFFLE-FREE softmax: softmax shift-invariance lets us fix m=0
// (scores bounded |s|<~26 by Cauchy-Schwarz -> exp(s) can't overflow fp32).
// p = c*exp(s); per-lane l accumulates its own pg-slice across tiles; ONE
// butterfly per wave at the end. No max tracking, no rescale, no per-tile DS
// shuffles -> per-tile DS = PV reads only (~33), serial chain = MFMA->exp.
__global__ __launch_bounds__(256, 1) void attn_partial(
    const float* __restrict__ q,
    const float* __restrict__ k_cache,
    const float* __restrict__ v_cache,
    const float* __restrict__ cntf,
    float* __restrict__ ws_out,   // [NPART][NB][NKVH][NG][NDV]
    float* __restrict__ ws_lse)   // [NPART][NB][NKVH][NG]
{
  const int bid   = blockIdx.x;
  const int r     = bid & 7;              // XCD swizzle: rank pinned per XCD
  const int kvh   = (bid >> 3) & 7;
  const int dh    = (bid >> 6) & 1;       // dv half (sibling co-resident)
  const int gp    = (bid >> 7) & 1;       // heads {2gp, 2gp+1}
  const int chunk = bid >> 8;             // 0..7

  const int tid  = threadIdx.x;
  const int wid  = tid >> 6;
  const int lane = tid & 63;
  const int col  = lane & 15;     // score: page-in-tile | PV: dim-block
  const int hq   = lane >> 4;     // score: k-quarter    | PV: qrow-quad

  // V half-dbuf (wave-private), union'd with the post-loop merge buffer.
  __shared__ float UN[4][2][1024];        // 32 KB
  __shared__ float Plds[4][16][20];       // [pg][qr], stride 20 (16B-aligned)
  __shared__ float Sml[4][16];            // per-wave row sums l

  // ---- Q A-frags (bf16, pre-scaled)
  bf16x8 qf[4];
  {
    const int qrow = col;
    const int b = qrow & 7;
    const int g = gp * 2 + (qrow >> 3);
    const float* qp = q + ((size_t)b * NH + kvh * NG + g) * ND + hq * 8;
#pragma unroll
    for (int st = 0; st < 4; ++st) {
      const float4 t0 = *(const float4*)(qp + st * 32);
      const float4 t1 = *(const float4*)(qp + st * 32 + 4);
      bf16x8 f;
      f[0] = f2bf(t0.x * QSCALE); f[1] = f2bf(t0.y * QSCALE);
      f[2] = f2bf(t0.z * QSCALE); f[3] = f2bf(t0.w * QSCALE);
      f[4] = f2bf(t1.x * QSCALE); f[5] = f2bf(t1.y * QSCALE);
      f[6] = f2bf(t1.z * QSCALE); f[7] = f2bf(t1.w * QSCALE);
      qf[st] = f;
    }
  }

  const int pg0w = chunk * CHUNK + wid * 64;   // wave's first page
  const float* Kb = k_cache + (size_t)r * NPAGE * KSTR + kvh * ND;
  const float* Vb = v_cache + (size_t)r * NPAGE * KSTR + kvh * NDV + dh * NDH;

  // prefetch macros: 4 stage + 8 K + 4 cw = 16 VMEM ops per tile
#define STAGE_V(bf, pgt)                                                     \
  {                                                                          \
    _Pragma("unroll")                                                        \
    for (int i = 0; i < 4; ++i) {                                            \
      const float* s_ =                                                      \
          Vb + (size_t)((pgt) + 4 * i + (lane >> 4)) * KSTR + (lane & 15) * 4; \
      gload_lds16(s_, &UN[wid][bf][i * 256]);                                \
    }                                                                        \
  }
#define KLOAD(dst, pgt)                                                      \
  {                                                                          \
    const float* kp_ = Kb + (size_t)((pgt) + col) * KSTR + hq * 8;           \
    _Pragma("unroll")                                                        \
    for (int st = 0; st < 4; ++st) {                                         \
      dst[2 * st]     = *(const float4*)(kp_ + st * 32);                     \
      dst[2 * st + 1] = *(const float4*)(kp_ + st * 32 + 4);                 \
    }                                                                        \
  }
#define CWLOAD(dst, pgt)                                                     \
  {                                                                          \
    _Pragma("unroll")                                                        \
    for (int rg = 0; rg < 4; ++rg)                                           \
      dst[rg] = cntf[((size_t)(r * NB + ((hq * 4 + rg) & 7))) * NPAGE +      \
                     (pgt) + col];                                           \
  }

  float4 kr[2][8];
  float  cwl[2][4];

  // prologue: prefetch tile 0
  STAGE_V(0, pg0w);
  KLOAD(kr[0], pg0w);
  CWLOAD(cwl[0], pg0w);

  float l[4] = {0.f, 0.f, 0.f, 0.f};     // per-lane pg-slice sums
  f32x4 O[4];                    // row hq*4+rg, dims dh*64 + col*4..+3
#pragma unroll
  for (int rg = 0; rg < 4; ++rg) O[rg] = (f32x4){0.f, 0.f, 0.f, 0.f};

#pragma unroll
  for (int t = 0; t < 4; ++t) {
    const int pgt = pg0w + t * 16;
    const int bf  = t & 1;

    if (t < 3) {                         // prefetch t+1, then counted wait
      STAGE_V(bf ^ 1, pgt + 16);
      KLOAD(kr[(t + 1) & 1], pgt + 16);
      CWLOAD(cwl[(t + 1) & 1], pgt + 16);
      asm volatile("s_waitcnt vmcnt(16)" ::: "memory");
    } else {
      asm volatile("s_waitcnt vmcnt(0)" ::: "memory");
    }

    // ---- QK^T: 4 MFMAs (K from prefetched regs, cvt to bf16 now)
    f32x4 acc = (f32x4){0.f, 0.f, 0.f, 0.f};
#pragma unroll
    for (int st = 0; st < 4; ++st) {
      const float4 a0 = kr[bf][2 * st];
      const float4 a1 = kr[bf][2 * st + 1];
      bf16x8 kf;
      kf[0] = f2bf(a0.x); kf[1] = f2bf(a0.y); kf[2] = f2bf(a0.z); kf[3] = f2bf(a0.w);
      kf[4] = f2bf(a1.x); kf[5] = f2bf(a1.y); kf[6] = f2bf(a1.z); kf[7] = f2bf(a1.w);
      acc = __builtin_amdgcn_mfma_f32_16x16x32_bf16(qf[st], kf, acc, 0, 0, 0);
    }

    // ---- shuffle-free weighted softmax terms (fixed shift m=0)
    float p[4];
#pragma unroll
    for (int rg = 0; rg < 4; ++rg) {
      p[rg] = cwl[bf][rg] * __expf(acc[rg]);
      l[rg] += p[rg];                    // own pg-slice; reduce once at end
    }
    {
      f32x4 pv = (f32x4){p[0], p[1], p[2], p[3]};
      *(f32x4*)&Plds[wid][col][hq * 4] = pv;   // rows hq*4..+3, page col
    }

    // ---- PV from LDS-staged half-V: 2 DS reads per page (1 V + 1 P)
#pragma unroll 4
    for (int pg = 0; pg < 16; ++pg) {
      const f32x4 pw = *(const f32x4*)&Plds[wid][pg][hq * 4];
      const f32x4 va = *(const f32x4*)&UN[wid][bf][pg * 64 + col * 4];
#pragma unroll
      for (int rg = 0; rg < 4; ++rg) O[rg] += pw[rg] * va;
    }
  }

  // ---- single end-of-wave butterfly: row sums over the 16 page-lanes
#pragma unroll
  for (int mk = 1; mk <= 8; mk <<= 1)
#pragma unroll
    for (int rg = 0; rg < 4; ++rg) l[rg] += __shfl_xor(l[rg], mk);

  // ---- merge: overlay Sacc onto the (now dead) V buffers
  __syncthreads();                       // all waves done reading UN
  float* Sacc = &UN[0][0][0];            // rows of 68 floats: [w*16+qr]
  if (col == 0) {
#pragma unroll
    for (int rg = 0; rg < 4; ++rg) Sml[wid][hq * 4 + rg] = l[rg];
  }
#pragma unroll
  for (int rg = 0; rg < 4; ++rg) {
    const int qr = hq * 4 + rg;
    *(f32x4*)&Sacc[(wid * 16 + qr) * 68 + col * 4] = O[rg];
  }
  __syncthreads();

  // ---- 4-way wave merge (plain sums: common shift m=0), write half-row
  const int qr = tid >> 4;        // 0..15
  const int db = tid & 15;        // 4 dims each
  float L = 0.f;
#pragma unroll
  for (int w = 0; w < 4; ++w) L += Sml[w][qr];
  const float inv = (L > 0.f) ? 1.f / L : 0.f;

  const int pi = r * NCH + chunk;
  const int b  = qr & 7;
  const int g  = gp * 2 + (qr >> 3);
  const size_t prow = (((size_t)pi * NB + b) * NKVH + kvh) * NG + g;
  {
    float4 o = make_float4(0.f, 0.f, 0.f, 0.f);
#pragma unroll
    for (int w = 0; w < 4; ++w) {
      const float* s4 = &Sacc[(w * 16 + qr) * 68 + db * 4];
      o.x += s4[0]; o.y += s4[1]; o.z += s4[2]; o.w += s4[3];
    }
    o.x *= inv; o.y *= inv; o.z *= inv; o.w *= inv;
    *(float4*)(ws_out + prow * NDV + dh * NDH + db * 4) = o;
  }
  // both dh siblings compute identical L: duplicate write is benign
  if (db == 0) ws_lse[prow] = (L > 0.f) ? __logf(L) : -1e30f;
}

// ---------------- combine over NPART partials per (b,kvh,g)
__global__ __launch_bounds__(128) void attn_combine(
    const float* __restrict__ ws_out,
    const float* __restrict__ ws_lse,
    float* __restrict__ out)
{
  const int bkg = blockIdx.x;
  const int d   = threadIdx.x;

  float mg = -INFINITY;
#pragma unroll 16
  for (int p = 0; p < NPART; ++p)
    mg = fmaxf(mg, ws_lse[p * PSTRIDE + bkg]);

  float denom = 0.f, acc = 0.f;
#pragma unroll 8
  for (int p = 0; p < NPART; ++p) {
    const float e = __expf(ws_lse[p * PSTRIDE + bkg] - mg);
    denom += e;
    acc += e * ws_out[((size_t)p * PSTRIDE + bkg) * NDV + d];
  }
  out[(size_t)bkg * NDV + d] = acc / denom;
}

extern "C" void kernel_launch(void* const* d_in, const int* in_sizes, int n_in,
                              void* d_out, int out_size, void* d_ws, size_t ws_size,
                              hipStream_t stream) {
  const float* q        = (const float*)d_in[0];
  const float* k_cache  = (const float*)d_in[1];
  const float* v_cache  = (const float*)d_in[2];
  const int*   kv_lens  = (const int*)d_in[3];
  const int*   bt       = (const int*)d_in[4];
  float* out = (float*)d_out;

  float* ws_out = (float*)d_ws;                                   // 8.39 MB
  float* ws_lse = ws_out + (size_t)NPART * PSTRIDE * NDV;         // 64 KB
  float* cntf   = ws_lse + NPART * PSTRIDE;                       // 512 KB

  build_counts<<<NR * NB, 256, 0, stream>>>(kv_lens, bt, cntf);
  attn_partial<<<NR * NKVH * NCH * 2 * 2, 256, 0, stream>>>(
      q, k_cache, v_cache, cntf, ws_out, ws_lse);
  attn_combine<<<NB * NKVH * NG, NDV, 0, stream>>>(ws_out, ws_lse, out);
}

// Round 15
// 58.568 us; speedup vs baseline: 1.1953x; 1.1578x over previous
//
#include <hip/hip_runtime.h>
#include <hip/hip_bf16.h>
#include <math.h>

#define NR 8
#define NB 8
#define NH 32
#define NKVH 8
#define NG 4
#define ND 128
#define NDV 128
#define NDH 64                // dv half handled per block
#define NPAGE 2048
#define KSTR (NKVH*ND)        // 1024 floats per page (all kvh slices)
#define NCH 8                 // page-chunks per rank
#define CHUNK 256             // pages per chunk
#define NPART (NR*NCH)        // 64 partial slots
#define PSTRIDE (NB*NKVH*NG)  // 256 output rows
#define QSCALE 0.088388347648318447f

typedef __attribute__((ext_vector_type(8))) short bf16x8;
typedef __attribute__((ext_vector_type(4))) float f32x4;

static __device__ __forceinline__ short f2bf(float x) {
  __hip_bfloat16 h = __float2bfloat16(x);
  return __builtin_bit_cast(short, h);
}

// async global->LDS, 16B per lane; LDS dest = wave-uniform base + lane*16
static __device__ __forceinline__ void gload_lds16(const float* g, float* l) {
  __builtin_amdgcn_global_load_lds(
      (__attribute__((address_space(1))) void*)g,
      (__attribute__((address_space(3))) void*)l, 16, 0, 0);
}

// ---------------- histogram: cntf[r][b][pg] = (float) multiplicity
__global__ __launch_bounds__(256) void build_counts(
    const int* __restrict__ kv_lens, const int* __restrict__ bt_all,
    float* __restrict__ cntf) {
  const int rb = blockIdx.x;             // r*NB + b
  __shared__ int h[NPAGE];
  for (int i = threadIdx.x; i < NPAGE; i += 256) h[i] = 0;
  __syncthreads();
  const int len = kv_lens[rb];
  const int* bt = bt_all + (size_t)rb * NPAGE;
  for (int i = threadIdx.x; i < len; i += 256) atomicAdd(&h[bt[i]], 1);
  __syncthreads();
  float* o = cntf + (size_t)rb * NPAGE;
  for (int i = threadIdx.x; i < NPAGE; i += 256) o[i] = (float)h[i];
}

// ---------------- MFMA weighted-stream attention partials.
// VOLUME-MINIMIZED: block = (r, kvh, chunk, dh) — BOTH g-pairs per block.
// Read volume: K 2x (dh only) + V 1x = 201 MB (was 403 MB with gp in grid).
// Per tile: 8 MFMAs (2 gp x 4 k-slices), shuffle-free m=0 softmax, PV from
// LDS-staged half-V serving both gp. 2-deep vmcnt(16) pipeline, 4-tile loop.
__global__ __launch_bounds__(256, 1) void attn_partial(
    const float* __restrict__ q,
    const float* __restrict__ k_cache,
    const float* __restrict__ v_cache,
    const float* __restrict__ cntf,
    float* __restrict__ ws_out,   // [NPART][NB][NKVH][NG][NDV]
    float* __restrict__ ws_lse)   // [NPART][NB][NKVH][NG]
{
  const int bid   = blockIdx.x;
  const int r     = bid & 7;              // XCD swizzle: rank pinned per XCD
  const int kvh   = (bid >> 3) & 7;
  const int dh    = (bid >> 6) & 1;       // dv half
  const int chunk = bid >> 7;             // 0..7

  const int tid  = threadIdx.x;
  const int wid  = tid >> 6;
  const int lane = tid & 63;
  const int col  = lane & 15;     // score: page-in-tile | PV: dim-block
  const int hq   = lane >> 4;     // score: k-quarter    | PV: qrow-quad

  // V half-dbuf (wave-private), oversized to also hold the merge buffer
  // (4 waves x 2 gp x 16 rows x 68 floats = 34816 B <= 35840 B).
  __shared__ float UN[4][2][1120];        // 35840 B
  __shared__ float Plds[4][2][16][20];    // [wid][gp][pg][qr] 10240 B
  __shared__ float Sml[4][2][16];         // per-wave row sums

  // ---- Q A-frags for BOTH g-pairs (bf16, pre-scaled)
  bf16x8 qf[2][4];
#pragma unroll
  for (int gp = 0; gp < 2; ++gp) {
    const int b = col & 7;
    const int g = gp * 2 + (col >> 3);
    const float* qp = q + ((size_t)b * NH + kvh * NG + g) * ND + hq * 8;
#pragma unroll
    for (int st = 0; st < 4; ++st) {
      const float4 t0 = *(const float4*)(qp + st * 32);
      const float4 t1 = *(const float4*)(qp + st * 32 + 4);
      bf16x8 f;
      f[0] = f2bf(t0.x * QSCALE); f[1] = f2bf(t0.y * QSCALE);
      f[2] = f2bf(t0.z * QSCALE); f[3] = f2bf(t0.w * QSCALE);
      f[4] = f2bf(t1.x * QSCALE); f[5] = f2bf(t1.y * QSCALE);
      f[6] = f2bf(t1.z * QSCALE); f[7] = f2bf(t1.w * QSCALE);
      qf[gp][st] = f;
    }
  }

  const int pg0w = chunk * CHUNK + wid * 64;   // wave's first page
  const float* Kb = k_cache + (size_t)r * NPAGE * KSTR + kvh * ND;
  const float* Vb = v_cache + (size_t)r * NPAGE * KSTR + kvh * NDV + dh * NDH;

  // prefetch macros: 4 stage + 8 K + 4 cw = 16 VMEM ops per tile
#define STAGE_V(bf, pgt)                                                     \
  {                                                                          \
    _Pragma("unroll")                                                        \
    for (int i = 0; i < 4; ++i) {                                            \
      const float* s_ =                                                      \
          Vb + (size_t)((pgt) + 4 * i + (lane >> 4)) * KSTR + (lane & 15) * 4; \
      gload_lds16(s_, &UN[wid][bf][i * 256]);                                \
    }                                                                        \
  }
#define KLOAD(dst, pgt)                                                      \
  {                                                                          \
    const float* kp_ = Kb + (size_t)((pgt) + col) * KSTR + hq * 8;           \
    _Pragma("unroll")                                                        \
    for (int st = 0; st < 4; ++st) {                                         \
      dst[2 * st]     = *(const float4*)(kp_ + st * 32);                     \
      dst[2 * st + 1] = *(const float4*)(kp_ + st * 32 + 4);                 \
    }                                                                        \
  }
#define CWLOAD(dst, pgt)                                                     \
  {                                                                          \
    _Pragma("unroll")                                                        \
    for (int rg = 0; rg < 4; ++rg)                                           \
      dst[rg] = cntf[((size_t)(r * NB + ((hq * 4 + rg) & 7))) * NPAGE +      \
                     (pgt) + col];                                           \
  }

  float4 kr[2][8];
  float  cwl[2][4];

  // prologue: prefetch tile 0
  STAGE_V(0, pg0w);
  KLOAD(kr[0], pg0w);
  CWLOAD(cwl[0], pg0w);

  float l[2][4] = {{0.f, 0.f, 0.f, 0.f}, {0.f, 0.f, 0.f, 0.f}};
  f32x4 O[2][4];                 // [gp][rg]: row hq*4+rg, dims dh*64+col*4..+3
#pragma unroll
  for (int gp = 0; gp < 2; ++gp)
#pragma unroll
    for (int rg = 0; rg < 4; ++rg) O[gp][rg] = (f32x4){0.f, 0.f, 0.f, 0.f};

#pragma unroll
  for (int t = 0; t < 4; ++t) {
    const int pgt = pg0w + t * 16;
    const int bf  = t & 1;

    if (t < 3) {                         // prefetch t+1, then counted wait
      STAGE_V(bf ^ 1, pgt + 16);
      KLOAD(kr[(t + 1) & 1], pgt + 16);
      CWLOAD(cwl[(t + 1) & 1], pgt + 16);
      asm volatile("s_waitcnt vmcnt(16)" ::: "memory");
    } else {
      asm volatile("s_waitcnt vmcnt(0)" ::: "memory");
    }

    // ---- QK^T: 8 MFMAs, 2 independent accumulator chains (both g-pairs)
    f32x4 acc0 = (f32x4){0.f, 0.f, 0.f, 0.f};
    f32x4 acc1 = (f32x4){0.f, 0.f, 0.f, 0.f};
#pragma unroll
    for (int st = 0; st < 4; ++st) {
      const float4 a0 = kr[bf][2 * st];
      const float4 a1 = kr[bf][2 * st + 1];
      bf16x8 kf;
      kf[0] = f2bf(a0.x); kf[1] = f2bf(a0.y); kf[2] = f2bf(a0.z); kf[3] = f2bf(a0.w);
      kf[4] = f2bf(a1.x); kf[5] = f2bf(a1.y); kf[6] = f2bf(a1.z); kf[7] = f2bf(a1.w);
      acc0 = __builtin_amdgcn_mfma_f32_16x16x32_bf16(qf[0][st], kf, acc0, 0, 0, 0);
      acc1 = __builtin_amdgcn_mfma_f32_16x16x32_bf16(qf[1][st], kf, acc1, 0, 0, 0);
    }

    // ---- shuffle-free weighted softmax terms (fixed shift m=0);
    // counts depend on b = qr&7 only -> shared by both gp planes.
    float p0[4], p1[4];
#pragma unroll
    for (int rg = 0; rg < 4; ++rg) {
      p0[rg] = cwl[bf][rg] * __expf(acc0[rg]);
      p1[rg] = cwl[bf][rg] * __expf(acc1[rg]);
      l[0][rg] += p0[rg];
      l[1][rg] += p1[rg];
    }
    *(f32x4*)&Plds[wid][0][col][hq * 4] = (f32x4){p0[0], p0[1], p0[2], p0[3]};
    *(f32x4*)&Plds[wid][1][col][hq * 4] = (f32x4){p1[0], p1[1], p1[2], p1[3]};

    // ---- PV from LDS-staged half-V: one V read serves both g-pairs
#pragma unroll 4
    for (int pg = 0; pg < 16; ++pg) {
      const f32x4 pw0 = *(const f32x4*)&Plds[wid][0][pg][hq * 4];
      const f32x4 pw1 = *(const f32x4*)&Plds[wid][1][pg][hq * 4];
      const f32x4 va  = *(const f32x4*)&UN[wid][t & 1][pg * 64 + col * 4];
#pragma unroll
      for (int rg = 0; rg < 4; ++rg) {
        O[0][rg] += pw0[rg] * va;
        O[1][rg] += pw1[rg] * va;
      }
    }
  }

  // ---- single end-of-wave butterfly per gp: row sums over 16 page-lanes
#pragma unroll
  for (int mk = 1; mk <= 8; mk <<= 1)
#pragma unroll
    for (int gp = 0; gp < 2; ++gp)
#pragma unroll
      for (int rg = 0; rg < 4; ++rg) l[gp][rg] += __shfl_xor(l[gp][rg], mk);

  // ---- merge: overlay Sacc onto the (now dead) V buffers
  __syncthreads();                       // all waves done reading UN
  float* Sacc = &UN[0][0][0];            // rows of 68 floats: [(w*2+gp)*16+qr]
  if (col == 0) {
#pragma unroll
    for (int gp = 0; gp < 2; ++gp)
#pragma unroll
      for (int rg = 0; rg < 4; ++rg) Sml[wid][gp][hq * 4 + rg] = l[gp][rg];
  }
#pragma unroll
  for (int gp = 0; gp < 2; ++gp)
#pragma unroll
    for (int rg = 0; rg < 4; ++rg) {
      const int row = (wid * 2 + gp) * 16 + hq * 4 + rg;
      *(f32x4*)&Sacc[row * 68 + col * 4] = O[gp][rg];
    }
  __syncthreads();

  // ---- 4-way wave merge (plain sums: common shift m=0), write half-row
  const int row = tid >> 3;       // 0..31 = gp*16 + qr
  const int db  = tid & 7;        // 8 dims each
  const int gpo = row >> 4;
  const int qr  = row & 15;
  float L = 0.f;
#pragma unroll
  for (int w = 0; w < 4; ++w) L += Sml[w][gpo][qr];
  const float inv = (L > 0.f) ? 1.f / L : 0.f;

  const int pi = r * NCH + chunk;
  const int b  = qr & 7;
  const int g  = gpo * 2 + (qr >> 3);
  const size_t prow = (((size_t)pi * NB + b) * NKVH + kvh) * NG + g;
  float* orow = ws_out + prow * NDV + dh * NDH + db * 8;
#pragma unroll
  for (int x = 0; x < 2; ++x) {
    float4 o = make_float4(0.f, 0.f, 0.f, 0.f);
#pragma unroll
    for (int w = 0; w < 4; ++w) {
      const float* s4 = &Sacc[((w * 2 + gpo) * 16 + qr) * 68 + db * 8 + x * 4];
      o.x += s4[0]; o.y += s4[1]; o.z += s4[2]; o.w += s4[3];
    }
    o.x *= inv; o.y *= inv; o.z *= inv; o.w *= inv;
    *(float4*)(orow + x * 4) = o;
  }
  // both dh siblings compute identical L: duplicate write is benign
  if (db == 0 && dh == 0) ws_lse[prow] = (L > 0.f) ? __logf(L) : -1e30f;
  if (db == 0 && dh == 1) ws_lse[prow] = (L > 0.f) ? __logf(L) : -1e30f;
}

// ---------------- combine over NPART partials per (b,kvh,g)
__global__ __launch_bounds__(128) void attn_combine(
    const float* __restrict__ ws_out,
    const float* __restrict__ ws_lse,
    float* __restrict__ out)
{
  const int bkg = blockIdx.x;
  const int d   = threadIdx.x;

  float mg = -INFINITY;
#pragma unroll 16
  for (int p = 0; p < NPART; ++p)
    mg = fmaxf(mg, ws_lse[p * PSTRIDE + bkg]);

  float denom = 0.f, acc = 0.f;
#pragma unroll 8
  for (int p = 0; p < NPART; ++p) {
    const float e = __expf(ws_lse[p * PSTRIDE + bkg] - mg);
    denom += e;
    acc += e * ws_out[((size_t)p * PSTRIDE + bkg) * NDV + d];
  }
  out[(size_t)bkg * NDV + d] = acc / denom;
}

extern "C" void kernel_launch(void* const* d_in, const int* in_sizes, int n_in,
                              void* d_out, int out_size, void* d_ws, size_t ws_size,
                              hipStream_t stream) {
  const float* q        = (const float*)d_in[0];
  const float* k_cache  = (const float*)d_in[1];
  const float* v_cache  = (const float*)d_in[2];
  const int*   kv_lens  = (const int*)d_in[3];
  const int*   bt       = (const int*)d_in[4];
  float* out = (float*)d_out;

  float* ws_out = (float*)d_ws;                                   // 8.39 MB
  float* ws_lse = ws_out + (size_t)NPART * PSTRIDE * NDV;         // 64 KB
  float* cntf   = ws_lse + NPART * PSTRIDE;                       // 512 KB

  build_counts<<<NR * NB, 256, 0, stream>>>(kv_lens, bt, cntf);
  attn_partial<<<NR * NKVH * 2 * NCH, 256, 0, stream>>>(
      q, k_cache, v_cache, cntf, ws_out, ws_lse);
  attn_combine<<<NB * NKVH * NG, NDV, 0, stream>>>(ws_out, ws_lse, out);
}

// Round 16
// 57.789 us; speedup vs baseline: 1.2115x; 1.0135x over previous
//
#include <hip/hip_runtime.h>
#include <hip/hip_bf16.h>
#include <math.h>

#define NR 8
#define NB 8
#define NH 32
#define NKVH 8
#define NG 4
#define ND 128
#define NDV 128
#define NDH 64                // dv half handled per block
#define NPAGE 2048
#define KSTR (NKVH*ND)        // 1024 floats per page (all kvh slices)
#define NCH 8                 // page-chunks per rank
#define CHUNK 256             // pages per chunk
#define NPART (NR*NCH)        // 64 partial slots
#define PSTRIDE (NB*NKVH*NG)  // 256 output rows
#define QSCALE 0.088388347648318447f

typedef __attribute__((ext_vector_type(8))) short bf16x8;
typedef __attribute__((ext_vector_type(4))) float f32x4;

static __device__ __forceinline__ short f2bf(float x) {
  __hip_bfloat16 h = __float2bfloat16(x);
  return __builtin_bit_cast(short, h);
}

// async global->LDS, 16B per lane; LDS dest = wave-uniform base + lane*16
static __device__ __forceinline__ void gload_lds16(const float* g, float* l) {
  __builtin_amdgcn_global_load_lds(
      (__attribute__((address_space(1))) void*)g,
      (__attribute__((address_space(3))) void*)l, 16, 0, 0);
}

// ---------------- histogram: cntf[r][b][pg] = (float) multiplicity
__global__ __launch_bounds__(256) void build_counts(
    const int* __restrict__ kv_lens, const int* __restrict__ bt_all,
    float* __restrict__ cntf) {
  const int rb = blockIdx.x;             // r*NB + b
  __shared__ int h[NPAGE];
  for (int i = threadIdx.x; i < NPAGE; i += 256) h[i] = 0;
  __syncthreads();
  const int len = kv_lens[rb];
  const int* bt = bt_all + (size_t)rb * NPAGE;
  for (int i = threadIdx.x; i < len; i += 256) atomicAdd(&h[bt[i]], 1);
  __syncthreads();
  float* o = cntf + (size_t)rb * NPAGE;
  for (int i = threadIdx.x; i < NPAGE; i += 256) o[i] = (float)h[i];
}

// ---------------- MFMA weighted-stream attention partials.
// EXACT 4-BLOCK/CU PACKING: LDS = 40,960 B exactly (160KB/4), grid 1024 =
// 4 blocks/CU lifetime -> ONE scheduling round, 16 waves/CU (was 3 resident
// + 1 straggler round). Flat LDS partitioning:
//   [0      .. 8192f)  V double-buffer: wid*2048 + bf*1024 + pg*64 + d
//   [8192f  .. 10240f) Plds stride 16:  8192 + wid*512 + gp*256 + pg*16 + qr
//   post-loop overlay:  merge O rows [0..8704f), Sml [8704f..8832f)
__global__ __launch_bounds__(256, 1) void attn_partial(
    const float* __restrict__ q,
    const float* __restrict__ k_cache,
    const float* __restrict__ v_cache,
    const float* __restrict__ cntf,
    float* __restrict__ ws_out,   // [NPART][NB][NKVH][NG][NDV]
    float* __restrict__ ws_lse)   // [NPART][NB][NKVH][NG]
{
  const int bid   = blockIdx.x;
  const int r     = bid & 7;              // XCD swizzle: rank pinned per XCD
  const int kvh   = (bid >> 3) & 7;
  const int dh    = (bid >> 6) & 1;       // dv half
  const int chunk = bid >> 7;             // 0..7

  const int tid  = threadIdx.x;
  const int wid  = tid >> 6;
  const int lane = tid & 63;
  const int col  = lane & 15;     // score: page-in-tile | PV: dim-block
  const int hq   = lane >> 4;     // score: k-quarter    | PV: qrow-quad

  __shared__ float LB[10240];     // 40,960 B EXACTLY — do not grow

  // ---- Q A-frags for BOTH g-pairs (bf16, pre-scaled)
  bf16x8 qf[2][4];
#pragma unroll
  for (int gp = 0; gp < 2; ++gp) {
    const int b = col & 7;
    const int g = gp * 2 + (col >> 3);
    const float* qp = q + ((size_t)b * NH + kvh * NG + g) * ND + hq * 8;
#pragma unroll
    for (int st = 0; st < 4; ++st) {
      const float4 t0 = *(const float4*)(qp + st * 32);
      const float4 t1 = *(const float4*)(qp + st * 32 + 4);
      bf16x8 f;
      f[0] = f2bf(t0.x * QSCALE); f[1] = f2bf(t0.y * QSCALE);
      f[2] = f2bf(t0.z * QSCALE); f[3] = f2bf(t0.w * QSCALE);
      f[4] = f2bf(t1.x * QSCALE); f[5] = f2bf(t1.y * QSCALE);
      f[6] = f2bf(t1.z * QSCALE); f[7] = f2bf(t1.w * QSCALE);
      qf[gp][st] = f;
    }
  }

  const int pg0w = chunk * CHUNK + wid * 64;   // wave's first page
  const float* Kb = k_cache + (size_t)r * NPAGE * KSTR + kvh * ND;
  const float* Vb = v_cache + (size_t)r * NPAGE * KSTR + kvh * NDV + dh * NDH;

  // prefetch macros: 4 stage + 8 K + 4 cw = 16 VMEM ops per tile
#define STAGE_V(bf, pgt)                                                     \
  {                                                                          \
    _Pragma("unroll")                                                        \
    for (int i = 0; i < 4; ++i) {                                            \
      const float* s_ =                                                      \
          Vb + (size_t)((pgt) + 4 * i + (lane >> 4)) * KSTR + (lane & 15) * 4; \
      gload_lds16(s_, &LB[wid * 2048 + (bf) * 1024 + i * 256]);              \
    }                                                                        \
  }
#define KLOAD(dst, pgt)                                                      \
  {                                                                          \
    const float* kp_ = Kb + (size_t)((pgt) + col) * KSTR + hq * 8;           \
    _Pragma("unroll")                                                        \
    for (int st = 0; st < 4; ++st) {                                         \
      dst[2 * st]     = *(const float4*)(kp_ + st * 32);                     \
      dst[2 * st + 1] = *(const float4*)(kp_ + st * 32 + 4);                 \
    }                                                                        \
  }
#define CWLOAD(dst, pgt)                                                     \
  {                                                                          \
    _Pragma("unroll")                                                        \
    for (int rg = 0; rg < 4; ++rg)                                           \
      dst[rg] = cntf[((size_t)(r * NB + ((hq * 4 + rg) & 7))) * NPAGE +      \
                     (pgt) + col];                                           \
  }

  float4 kr[2][8];
  float  cwl[2][4];

  // prologue: prefetch tile 0
  STAGE_V(0, pg0w);
  KLOAD(kr[0], pg0w);
  CWLOAD(cwl[0], pg0w);

  float l[2][4] = {{0.f, 0.f, 0.f, 0.f}, {0.f, 0.f, 0.f, 0.f}};
  f32x4 O[2][4];                 // [gp][rg]: row hq*4+rg, dims dh*64+col*4..+3
#pragma unroll
  for (int gp = 0; gp < 2; ++gp)
#pragma unroll
    for (int rg = 0; rg < 4; ++rg) O[gp][rg] = (f32x4){0.f, 0.f, 0.f, 0.f};

#pragma unroll
  for (int t = 0; t < 4; ++t) {
    const int pgt = pg0w + t * 16;
    const int bf  = t & 1;

    if (t < 3) {                         // prefetch t+1, then counted wait
      STAGE_V(bf ^ 1, pgt + 16);
      KLOAD(kr[(t + 1) & 1], pgt + 16);
      CWLOAD(cwl[(t + 1) & 1], pgt + 16);
      asm volatile("s_waitcnt vmcnt(16)" ::: "memory");
    } else {
      asm volatile("s_waitcnt vmcnt(0)" ::: "memory");
    }

    // ---- QK^T: 8 MFMAs, 2 independent accumulator chains (both g-pairs)
    f32x4 acc0 = (f32x4){0.f, 0.f, 0.f, 0.f};
    f32x4 acc1 = (f32x4){0.f, 0.f, 0.f, 0.f};
#pragma unroll
    for (int st = 0; st < 4; ++st) {
      const float4 a0 = kr[bf][2 * st];
      const float4 a1 = kr[bf][2 * st + 1];
      bf16x8 kf;
      kf[0] = f2bf(a0.x); kf[1] = f2bf(a0.y); kf[2] = f2bf(a0.z); kf[3] = f2bf(a0.w);
      kf[4] = f2bf(a1.x); kf[5] = f2bf(a1.y); kf[6] = f2bf(a1.z); kf[7] = f2bf(a1.w);
      acc0 = __builtin_amdgcn_mfma_f32_16x16x32_bf16(qf[0][st], kf, acc0, 0, 0, 0);
      acc1 = __builtin_amdgcn_mfma_f32_16x16x32_bf16(qf[1][st], kf, acc1, 0, 0, 0);
    }

    // ---- shuffle-free weighted softmax terms (fixed shift m=0);
    // counts depend on b = qr&7 only -> shared by both gp planes.
    float p0[4], p1[4];
#pragma unroll
    for (int rg = 0; rg < 4; ++rg) {
      p0[rg] = cwl[bf][rg] * __expf(acc0[rg]);
      p1[rg] = cwl[bf][rg] * __expf(acc1[rg]);
      l[0][rg] += p0[rg];
      l[1][rg] += p1[rg];
    }
    *(f32x4*)&LB[8192 + wid * 512 + 0 * 256 + col * 16 + hq * 4] =
        (f32x4){p0[0], p0[1], p0[2], p0[3]};
    *(f32x4*)&LB[8192 + wid * 512 + 1 * 256 + col * 16 + hq * 4] =
        (f32x4){p1[0], p1[1], p1[2], p1[3]};

    // ---- PV from LDS-staged half-V: one V read serves both g-pairs
#pragma unroll 4
    for (int pg = 0; pg < 16; ++pg) {
      const f32x4 pw0 = *(const f32x4*)&LB[8192 + wid * 512 + pg * 16 + hq * 4];
      const f32x4 pw1 = *(const f32x4*)&LB[8192 + wid * 512 + 256 + pg * 16 + hq * 4];
      const f32x4 va  = *(const f32x4*)&LB[wid * 2048 + bf * 1024 + pg * 64 + col * 4];
#pragma unroll
      for (int rg = 0; rg < 4; ++rg) {
        O[0][rg] += pw0[rg] * va;
        O[1][rg] += pw1[rg] * va;
      }
    }
  }

  // ---- single end-of-wave butterfly per gp: row sums over 16 page-lanes
#pragma unroll
  for (int mk = 1; mk <= 8; mk <<= 1)
#pragma unroll
    for (int gp = 0; gp < 2; ++gp)
#pragma unroll
      for (int rg = 0; rg < 4; ++rg) l[gp][rg] += __shfl_xor(l[gp][rg], mk);

  // ---- merge: overlay O rows + Sml onto the (now dead) V/P regions
  __syncthreads();                       // all waves done with LB loop data
  if (col == 0) {
#pragma unroll
    for (int gp = 0; gp < 2; ++gp)
#pragma unroll
      for (int rg = 0; rg < 4; ++rg)
        LB[8704 + wid * 32 + gp * 16 + hq * 4 + rg] = l[gp][rg];
  }
#pragma unroll
  for (int gp = 0; gp < 2; ++gp)
#pragma unroll
    for (int rg = 0; rg < 4; ++rg) {
      const int row = (wid * 2 + gp) * 16 + hq * 4 + rg;
      *(f32x4*)&LB[row * 68 + col * 4] = O[gp][rg];
    }
  __syncthreads();

  // ---- 4-way wave merge (plain sums: common shift m=0), write half-row
  const int row = tid >> 3;       // 0..31 = gp*16 + qr
  const int db  = tid & 7;        // 8 dims each
  const int gpo = row >> 4;
  const int qr  = row & 15;
  float L = 0.f;
#pragma unroll
  for (int w = 0; w < 4; ++w) L += LB[8704 + w * 32 + gpo * 16 + qr];
  const float inv = (L > 0.f) ? 1.f / L : 0.f;

  const int pi = r * NCH + chunk;
  const int b  = qr & 7;
  const int g  = gpo * 2 + (qr >> 3);
  const size_t prow = (((size_t)pi * NB + b) * NKVH + kvh) * NG + g;
  float* orow = ws_out + prow * NDV + dh * NDH + db * 8;
#pragma unroll
  for (int x = 0; x < 2; ++x) {
    float4 o = make_float4(0.f, 0.f, 0.f, 0.f);
#pragma unroll
    for (int w = 0; w < 4; ++w) {
      const float* s4 = &LB[((w * 2 + gpo) * 16 + qr) * 68 + db * 8 + x * 4];
      o.x += s4[0]; o.y += s4[1]; o.z += s4[2]; o.w += s4[3];
    }
    o.x *= inv; o.y *= inv; o.z *= inv; o.w *= inv;
    *(float4*)(orow + x * 4) = o;
  }
  // both dh siblings compute identical L: duplicate write is benign
  if (db == 0) ws_lse[prow] = (L > 0.f) ? __logf(L) : -1e30f;
}

// ---------------- combine over NPART partials per (b,kvh,g)
__global__ __launch_bounds__(128) void attn_combine(
    const float* __restrict__ ws_out,
    const float* __restrict__ ws_lse,
    float* __restrict__ out)
{
  const int bkg = blockIdx.x;
  const int d   = threadIdx.x;

  float mg = -INFINITY;
#pragma unroll 16
  for (int p = 0; p < NPART; ++p)
    mg = fmaxf(mg, ws_lse[p * PSTRIDE + bkg]);

  float denom = 0.f, acc = 0.f;
#pragma unroll 8
  for (int p = 0; p < NPART; ++p) {
    const float e = __expf(ws_lse[p * PSTRIDE + bkg] - mg);
    denom += e;
    acc += e * ws_out[((size_t)p * PSTRIDE + bkg) * NDV + d];
  }
  out[(size_t)bkg * NDV + d] = acc / denom;
}

extern "C" void kernel_launch(void* const* d_in, const int* in_sizes, int n_in,
                              void* d_out, int out_size, void* d_ws, size_t ws_size,
                              hipStream_t stream) {
  const float* q        = (const float*)d_in[0];
  const float* k_cache  = (const float*)d_in[1];
  const float* v_cache  = (const float*)d_in[2];
  const int*   kv_lens  = (const int*)d_in[3];
  const int*   bt       = (const int*)d_in[4];
  float* out = (float*)d_out;

  float* ws_out = (float*)d_ws;                                   // 8.39 MB
  float* ws_lse = ws_out + (size_t)NPART * PSTRIDE * NDV;         // 64 KB
  float* cntf   = ws_lse + NPART * PSTRIDE;                       // 512 KB

  build_counts<<<NR * NB, 256, 0, stream>>>(kv_lens, bt, cntf);
  attn_partial<<<NR * NKVH * 2 * NCH, 256, 0, stream>>>(
      q, k_cache, v_cache, cntf, ws_out, ws_lse);
  attn_combine<<<NB * NKVH * NG, NDV, 0, stream>>>(ws_out, ws_lse, out);
}